// Round 1
// baseline (5865.881 us; speedup 1.0000x reference)
//
#include <hip/hip_runtime.h>

#define NN 100000
#define NE 1600000
#define NG 1024

// ---------------------------------------------------------------- degree ----
__global__ __launch_bounds__(256) void k_deg(const int* __restrict__ dst,
                                             float* __restrict__ deg) {
  int e = blockIdx.x * 256 + threadIdx.x;
  if (e < NE) unsafeAtomicAdd(&deg[dst[e]], 1.0f);
}

__global__ __launch_bounds__(256) void k_invdeg(float* __restrict__ deg) {
  int i = blockIdx.x * 256 + threadIdx.x;
  if (i < NN) deg[i] = 1.0f / fmaxf(deg[i], 1.0f);
}

// ------------------------------------------------- edge scatter-aggregate ----
// F: [NN x 64] features; agg[dst] += F[src].  16 threads/edge, float4 lanes.
__global__ __launch_bounds__(256) void k_agg4(const float* __restrict__ F,
                                              const int* __restrict__ src,
                                              const int* __restrict__ dst,
                                              float* __restrict__ agg) {
  int idx = blockIdx.x * 256 + threadIdx.x;  // grid sized to exactly NE*16
  int e = idx >> 4;
  int q = (idx & 15) << 2;
  int s = src[e], d = dst[e];
  const float4 v = *reinterpret_cast<const float4*>(&F[(size_t)s * 64 + q]);
  float* p = &agg[(size_t)d * 64 + q];
  unsafeAtomicAdd(p + 0, v.x);
  unsafeAtomicAdd(p + 1, v.y);
  unsafeAtomicAdd(p + 2, v.z);
  unsafeAtomicAdd(p + 3, v.w);
}

// ----------------------------------------------------------------- GEMM -----
// OUT[M x 64 cols (at colOff, stride outStride)] = act( A @ W + bias )
// dual mode (inv != null):  A = [S0*inv | S1]  (each M x 64), W = [[WL],[WR]]
//                           stacked rows, W col block at colOff, row stride wStride.
// single mode:              A = S0 (M x 128), W = WL (128 x wStride), cols at colOff.
#define FMA16(A, W)                                                            \
  acc[0][0] += (A).x * (W).x; acc[0][1] += (A).x * (W).y;                      \
  acc[0][2] += (A).x * (W).z; acc[0][3] += (A).x * (W).w;                      \
  acc[1][0] += (A).y * (W).x; acc[1][1] += (A).y * (W).y;                      \
  acc[1][2] += (A).y * (W).z; acc[1][3] += (A).y * (W).w;                      \
  acc[2][0] += (A).z * (W).x; acc[2][1] += (A).z * (W).y;                      \
  acc[2][2] += (A).z * (W).z; acc[2][3] += (A).z * (W).w;                      \
  acc[3][0] += (A).w * (W).x; acc[3][1] += (A).w * (W).y;                      \
  acc[3][2] += (A).w * (W).z; acc[3][3] += (A).w * (W).w;

__global__ __launch_bounds__(256) void k_gemm64(
    const float* __restrict__ S0, const float* __restrict__ S1,
    const float* __restrict__ inv,
    const float* __restrict__ WL, const float* __restrict__ WR,
    int wStride, int colOff,
    const float* __restrict__ bias, int doRelu,
    float* __restrict__ OUT, int outStride, int M) {
  // sA transposed [k2][m], m-dim padded 64->68: LDS write stride 17 banks (2-way,
  // free) and 16B-aligned ds_read_b128 on the read side.
  __shared__ float sA[64 * 68];
  __shared__ float sW[128 * 64];
  __shared__ float sB[64];
  const int tid = threadIdx.x;
  const bool dual = (inv != nullptr);

  for (int i = tid; i < 128 * 64; i += 256) {
    int k = i >> 6, c = i & 63;
    float w;
    if (dual)
      w = (k < 64) ? WL[k * wStride + colOff + c]
                   : WR[(k - 64) * wStride + colOff + c];
    else
      w = WL[k * wStride + colOff + c];
    sW[i] = w;
  }
  if (tid < 64) sB[tid] = bias ? bias[colOff + tid] : 0.0f;

  const int m0 = blockIdx.x * 64;
  const int tx = tid & 15, ty = tid >> 4;

  // stage A, K-half 0
  for (int i = tid; i < 64 * 64; i += 256) {
    int m = i >> 6, k2 = i & 63;
    int row = m0 + m;
    float v = 0.0f;
    if (row < M)
      v = dual ? S0[(size_t)row * 64 + k2] * inv[row]
               : S0[(size_t)row * 128 + k2];
    sA[k2 * 68 + m] = v;
  }
  __syncthreads();

  float acc[4][4];
#pragma unroll
  for (int i = 0; i < 4; ++i)
#pragma unroll
    for (int j = 0; j < 4; ++j) acc[i][j] = sB[tx * 4 + j];

#pragma unroll 8
  for (int k2 = 0; k2 < 64; ++k2) {
    const float4 a = *reinterpret_cast<const float4*>(&sA[k2 * 68 + ty * 4]);
    const float4 w = *reinterpret_cast<const float4*>(&sW[k2 * 64 + tx * 4]);
    FMA16(a, w)
  }
  __syncthreads();

  // stage A, K-half 1
  for (int i = tid; i < 64 * 64; i += 256) {
    int m = i >> 6, k2 = i & 63;
    int row = m0 + m;
    float v = 0.0f;
    if (row < M)
      v = dual ? S1[(size_t)row * 64 + k2]
               : S0[(size_t)row * 128 + 64 + k2];
    sA[k2 * 68 + m] = v;
  }
  __syncthreads();

#pragma unroll 8
  for (int k2 = 0; k2 < 64; ++k2) {
    const float4 a = *reinterpret_cast<const float4*>(&sA[k2 * 68 + ty * 4]);
    const float4 w = *reinterpret_cast<const float4*>(&sW[(64 + k2) * 64 + tx * 4]);
    FMA16(a, w)
  }

#pragma unroll
  for (int i = 0; i < 4; ++i) {
    int row = m0 + ty * 4 + i;
    if (row < M) {
      float4 o = make_float4(acc[i][0], acc[i][1], acc[i][2], acc[i][3]);
      if (doRelu) {
        o.x = fmaxf(o.x, 0.0f); o.y = fmaxf(o.y, 0.0f);
        o.z = fmaxf(o.z, 0.0f); o.w = fmaxf(o.w, 0.0f);
      }
      *reinterpret_cast<float4*>(&OUT[(size_t)row * outStride + colOff + tx * 4]) = o;
    }
  }
}

// --------------------------------------------- layer-2 epilogue (combine) ---
// H = relu(agg*inv + bias + Z)   (all [NN x 64])
__global__ __launch_bounds__(256) void k_combine(
    const float* __restrict__ agg, const float* __restrict__ inv,
    const float* __restrict__ bias, const float* __restrict__ Z,
    float* __restrict__ H) {
  int idx = blockIdx.x * 256 + threadIdx.x;  // grid = NN*16 threads
  int n = idx >> 4;
  int q = (idx & 15) << 2;
  float iv = inv[n];
  const float4 a = *reinterpret_cast<const float4*>(&agg[(size_t)n * 64 + q]);
  const float4 z = *reinterpret_cast<const float4*>(&Z[(size_t)n * 64 + q]);
  const float4 b = *reinterpret_cast<const float4*>(&bias[q]);
  float4 h;
  h.x = fmaxf(fmaf(a.x, iv, b.x) + z.x, 0.0f);
  h.y = fmaxf(fmaf(a.y, iv, b.y) + z.y, 0.0f);
  h.z = fmaxf(fmaf(a.z, iv, b.z) + z.z, 0.0f);
  h.w = fmaxf(fmaf(a.w, iv, b.w) + z.w, 0.0f);
  *reinterpret_cast<float4*>(&H[(size_t)n * 64 + q]) = h;
}

// ------------------------------------------------------------------ pool ----
__global__ __launch_bounds__(256) void k_pool(const float* __restrict__ H,
                                              const int* __restrict__ batch,
                                              float* __restrict__ gsum,
                                              float* __restrict__ gcnt) {
  int idx = blockIdx.x * 256 + threadIdx.x;  // NN*16 threads
  int n = idx >> 4;
  int q = (idx & 15) << 2;
  int b = batch[n];
  const float4 v = *reinterpret_cast<const float4*>(&H[(size_t)n * 64 + q]);
  float* p = &gsum[(size_t)b * 64 + q];
  unsafeAtomicAdd(p + 0, v.x);
  unsafeAtomicAdd(p + 1, v.y);
  unsafeAtomicAdd(p + 2, v.z);
  unsafeAtomicAdd(p + 3, v.w);
  if ((idx & 15) == 0) unsafeAtomicAdd(&gcnt[b], 1.0f);
}

// ------------------------------------------------------------------- MLP ----
__global__ __launch_bounds__(64) void k_mlp(
    const float* __restrict__ gsum, const float* __restrict__ gcnt,
    const float* __restrict__ w1, const float* __restrict__ b1,
    const float* __restrict__ w2, const float* __restrict__ b2,
    const float* __restrict__ w3, const float* __restrict__ b3,
    const float* __restrict__ w4, const float* __restrict__ b4,
    float* __restrict__ out) {
  __shared__ float sg[64], s1[64], s2[32], s3[32];
  int g = blockIdx.x, t = threadIdx.x;
  float cnt = fmaxf(gcnt[g], 1.0f);
  sg[t] = gsum[(size_t)g * 64 + t] / cnt;
  __syncthreads();
  float acc = b1[t];
  for (int k = 0; k < 64; ++k) acc += sg[k] * w1[k * 64 + t];
  s1[t] = fmaxf(acc, 0.0f);
  __syncthreads();
  if (t < 32) {
    acc = b2[t];
    for (int k = 0; k < 64; ++k) acc += s1[k] * w2[k * 32 + t];
    s2[t] = fmaxf(acc, 0.0f);
  }
  __syncthreads();
  if (t < 32) {
    acc = b3[t];
    for (int k = 0; k < 32; ++k) acc += s2[k] * w3[k * 32 + t];
    s3[t] = fmaxf(acc, 0.0f);
  }
  __syncthreads();
  if (t == 0) {
    acc = b4[0];
    for (int k = 0; k < 32; ++k) acc += s3[k] * w4[k];
    out[g] = acc;
  }
}

// ---------------------------------------------------------------- launch ----
extern "C" void kernel_launch(void* const* d_in, const int* in_sizes, int n_in,
                              void* d_out, int out_size, void* d_ws,
                              size_t ws_size, hipStream_t stream) {
  const float* x     = (const float*)d_in[0];
  const int*   ei    = (const int*)d_in[1];
  const int*   batch = (const int*)d_in[2];
  const int* src = ei;
  const int* dst = ei + NE;

  const float* c1_wl = (const float*)d_in[3];
  const float* c1_bl = (const float*)d_in[4];
  const float* c1_wr = (const float*)d_in[5];
  const float* c2_wl = (const float*)d_in[6];
  const float* c2_bl = (const float*)d_in[7];
  const float* c2_wr = (const float*)d_in[8];
  const float* c3_wl = (const float*)d_in[9];
  const float* c3_bl = (const float*)d_in[10];
  const float* c3_wr = (const float*)d_in[11];
  const float* c4_wl = (const float*)d_in[12];
  const float* c4_bl = (const float*)d_in[13];
  const float* c4_wr = (const float*)d_in[14];
  const float* l1w = (const float*)d_in[15];
  const float* l1b = (const float*)d_in[16];
  const float* l2w = (const float*)d_in[17];
  const float* l2b = (const float*)d_in[18];
  const float* l3w = (const float*)d_in[19];
  const float* l3b = (const float*)d_in[20];
  const float* l4w = (const float*)d_in[21];
  const float* l4b = (const float*)d_in[22];

  float* ws = (float*)d_ws;
  float* inv  = ws;                         // NN
  float* agg  = inv + NN;                   // NN*64
  float* h1   = agg + (size_t)NN * 64;      // NN*128
  float* U    = h1 + (size_t)NN * 128;      // NN*64
  float* V    = U + (size_t)NN * 64;        // NN*64
  float* gsum = V + (size_t)NN * 64;        // NG*64
  float* gcnt = gsum + (size_t)NG * 64;     // NG

  const int gE   = NE / 256;         // 6250   (deg)
  const int gA   = NE * 16 / 256;    // 100000 (agg4)
  const int gN16 = NN * 16 / 256;    // 6250   (combine/pool)
  const int gM   = (NN + 63) / 64;   // 1563   (gemm)

  hipMemsetAsync(inv, 0, (size_t)NN * 4, stream);
  hipMemsetAsync(agg, 0, (size_t)NN * 64 * 4, stream);
  hipMemsetAsync(gsum, 0, (size_t)(NG * 64 + NG) * 4, stream);

  k_deg<<<gE, 256, 0, stream>>>(dst, inv);
  k_invdeg<<<(NN + 255) / 256, 256, 0, stream>>>(inv);

  // ---- layer 1: h1 = relu([agg(x)*inv | x] @ [[c1_wl],[c1_wr]] + c1_bl)
  k_agg4<<<gA, 256, 0, stream>>>(x, src, dst, agg);
  k_gemm64<<<gM, 256, 0, stream>>>(agg, x, inv, c1_wl, c1_wr, 128, 0,  c1_bl, 1, h1, 128, NN);
  k_gemm64<<<gM, 256, 0, stream>>>(agg, x, inv, c1_wl, c1_wr, 128, 64, c1_bl, 1, h1, 128, NN);

  // ---- layer 2 (post-aggregate): yl = h1@wl (U), zr = h1@wr (V)
  k_gemm64<<<gM, 256, 0, stream>>>(h1, nullptr, nullptr, c2_wl, nullptr, 64, 0, nullptr, 0, U, 64, NN);
  k_gemm64<<<gM, 256, 0, stream>>>(h1, nullptr, nullptr, c2_wr, nullptr, 64, 0, nullptr, 0, V, 64, NN);
  hipMemsetAsync(agg, 0, (size_t)NN * 64 * 4, stream);
  k_agg4<<<gA, 256, 0, stream>>>(U, src, dst, agg);
  k_combine<<<gN16, 256, 0, stream>>>(agg, inv, c2_bl, V, U);  // U = h2

  // ---- layer 3: h3 (V) = relu([agg(h2)*inv | h2] @ [[c3_wl],[c3_wr]] + c3_bl)
  hipMemsetAsync(agg, 0, (size_t)NN * 64 * 4, stream);
  k_agg4<<<gA, 256, 0, stream>>>(U, src, dst, agg);
  k_gemm64<<<gM, 256, 0, stream>>>(agg, U, inv, c3_wl, c3_wr, 64, 0, c3_bl, 1, V, 64, NN);

  // ---- layer 4: h4 (U) = relu([agg(h3)*inv | h3] @ [[c4_wl],[c4_wr]] + c4_bl)
  hipMemsetAsync(agg, 0, (size_t)NN * 64 * 4, stream);
  k_agg4<<<gA, 256, 0, stream>>>(V, src, dst, agg);
  k_gemm64<<<gM, 256, 0, stream>>>(agg, V, inv, c4_wl, c4_wr, 64, 0, c4_bl, 1, U, 64, NN);

  // ---- pool + MLP
  k_pool<<<gN16, 256, 0, stream>>>(U, batch, gsum, gcnt);
  k_mlp<<<NG, 64, 0, stream>>>(gsum, gcnt, l1w, l1b, l2w, l2b, l3w, l3b, l4w, l4b,
                               (float*)d_out);
}

// Round 2
// 1073.439 us; speedup vs baseline: 5.4646x; 5.4646x over previous
//
#include <hip/hip_runtime.h>

#define NN 100000
#define NE 1600000
#define NG 1024
#define NBLK_SCAN ((NN + 255) / 256)  // 391

// ------------------------------------------------------------- CSR build ----
__global__ __launch_bounds__(256) void k_count(const int* __restrict__ dst,
                                               int* __restrict__ cnt) {
  int e = blockIdx.x * 256 + threadIdx.x;
  if (e < NE) atomicAdd(&cnt[dst[e]], 1);
}

// exclusive scan, stage 1: per-block scan of cnt -> off(excl within block), bsum
__global__ __launch_bounds__(256) void k_scan1(const int* __restrict__ cnt,
                                               int* __restrict__ off,
                                               int* __restrict__ bsum) {
  __shared__ int s[256];
  int tid = threadIdx.x;
  int i = blockIdx.x * 256 + tid;
  int v = (i < NN) ? cnt[i] : 0;
  s[tid] = v;
  __syncthreads();
  for (int d = 1; d < 256; d <<= 1) {
    int t = (tid >= d) ? s[tid - d] : 0;
    __syncthreads();
    s[tid] += t;
    __syncthreads();
  }
  if (i < NN) off[i] = s[tid] - v;  // exclusive
  if (tid == 255) bsum[blockIdx.x] = s[255];
}

// stage 2: single-block exclusive scan of the 391 block sums
__global__ __launch_bounds__(512) void k_scan2(int* __restrict__ bsum) {
  __shared__ int s[512];
  int tid = threadIdx.x;
  int v = (tid < NBLK_SCAN) ? bsum[tid] : 0;
  s[tid] = v;
  __syncthreads();
  for (int d = 1; d < 512; d <<= 1) {
    int t = (tid >= d) ? s[tid - d] : 0;
    __syncthreads();
    s[tid] += t;
    __syncthreads();
  }
  if (tid < NBLK_SCAN) bsum[tid] = s[tid] - v;  // exclusive
}

// stage 3: add block offsets; copy to cursor; set off[NN]
__global__ __launch_bounds__(256) void k_scan3(int* __restrict__ off,
                                               const int* __restrict__ bsum,
                                               int* __restrict__ cursor) {
  int i = blockIdx.x * 256 + threadIdx.x;
  if (i < NN) {
    int o = off[i] + bsum[blockIdx.x];
    off[i] = o;
    cursor[i] = o;
  }
  if (i == 0) off[NN] = NE;
}

__global__ __launch_bounds__(256) void k_fill(const int* __restrict__ src,
                                              const int* __restrict__ dst,
                                              int* __restrict__ cursor,
                                              int* __restrict__ csr) {
  int e = blockIdx.x * 256 + threadIdx.x;
  if (e < NE) {
    int d = dst[e];
    int pos = atomicAdd(&cursor[d], 1);
    csr[pos] = src[e];
  }
}

__global__ __launch_bounds__(256) void k_invdeg(const int* __restrict__ cnt,
                                                float* __restrict__ inv) {
  int i = blockIdx.x * 256 + threadIdx.x;
  if (i < NN) inv[i] = 1.0f / fmaxf((float)cnt[i], 1.0f);
}

// --------------------------------------------------------- gather-aggregate -
// agg[n] = inv[n] * sum_{e in edges(n)} F[csr[e]]   (64 ch, 16 thr/node)
__global__ __launch_bounds__(256) void k_gather(const float* __restrict__ F,
                                                const int* __restrict__ csr,
                                                const int* __restrict__ off,
                                                const float* __restrict__ inv,
                                                float* __restrict__ agg) {
  int idx = blockIdx.x * 256 + threadIdx.x;  // grid = NN*16 threads
  int n = idx >> 4;
  int q = (idx & 15) << 2;
  int beg = off[n], end = off[n + 1];
  float4 acc = make_float4(0.f, 0.f, 0.f, 0.f);
  for (int e = beg; e < end; ++e) {
    int s = csr[e];
    const float4 v = *reinterpret_cast<const float4*>(&F[(size_t)s * 64 + q]);
    acc.x += v.x; acc.y += v.y; acc.z += v.z; acc.w += v.w;
  }
  float iv = inv[n];
  acc.x *= iv; acc.y *= iv; acc.z *= iv; acc.w *= iv;
  *reinterpret_cast<float4*>(&agg[(size_t)n * 64 + q]) = acc;
}

// ----------------------------------------------------------------- GEMM -----
// OUT[M x 64 cols (at colOff, stride outStride)] = act( A @ W + bias )
// dual==1:  A = [S0 | S1] (each M x 64, stride 64), W = [[WL],[WR]] stacked,
//           col block at colOff, row stride wStride.
// dual==0:  A = S0 (M x 128), W = WL (128 x wStride), cols at colOff.
#define FMA16(A, W)                                                            \
  acc[0][0] += (A).x * (W).x; acc[0][1] += (A).x * (W).y;                      \
  acc[0][2] += (A).x * (W).z; acc[0][3] += (A).x * (W).w;                      \
  acc[1][0] += (A).y * (W).x; acc[1][1] += (A).y * (W).y;                      \
  acc[1][2] += (A).y * (W).z; acc[1][3] += (A).y * (W).w;                      \
  acc[2][0] += (A).z * (W).x; acc[2][1] += (A).z * (W).y;                      \
  acc[2][2] += (A).z * (W).z; acc[2][3] += (A).z * (W).w;                      \
  acc[3][0] += (A).w * (W).x; acc[3][1] += (A).w * (W).y;                      \
  acc[3][2] += (A).w * (W).z; acc[3][3] += (A).w * (W).w;

__global__ __launch_bounds__(256) void k_gemm64(
    const float* __restrict__ S0, const float* __restrict__ S1, int dual,
    const float* __restrict__ WL, const float* __restrict__ WR,
    int wStride, int colOff,
    const float* __restrict__ bias, int doRelu,
    float* __restrict__ OUT, int outStride, int M) {
  __shared__ float sA[64 * 68];
  __shared__ float sW[128 * 64];
  __shared__ float sB[64];
  const int tid = threadIdx.x;

  for (int i = tid; i < 128 * 64; i += 256) {
    int k = i >> 6, c = i & 63;
    float w;
    if (dual)
      w = (k < 64) ? WL[k * wStride + colOff + c]
                   : WR[(k - 64) * wStride + colOff + c];
    else
      w = WL[k * wStride + colOff + c];
    sW[i] = w;
  }
  if (tid < 64) sB[tid] = bias ? bias[colOff + tid] : 0.0f;

  const int m0 = blockIdx.x * 64;
  const int tx = tid & 15, ty = tid >> 4;

  // stage A, K-half 0
  for (int i = tid; i < 64 * 64; i += 256) {
    int m = i >> 6, k2 = i & 63;
    int row = m0 + m;
    float v = 0.0f;
    if (row < M)
      v = dual ? S0[(size_t)row * 64 + k2] : S0[(size_t)row * 128 + k2];
    sA[k2 * 68 + m] = v;
  }
  __syncthreads();

  float acc[4][4];
#pragma unroll
  for (int i = 0; i < 4; ++i)
#pragma unroll
    for (int j = 0; j < 4; ++j) acc[i][j] = sB[tx * 4 + j];

#pragma unroll 8
  for (int k2 = 0; k2 < 64; ++k2) {
    const float4 a = *reinterpret_cast<const float4*>(&sA[k2 * 68 + ty * 4]);
    const float4 w = *reinterpret_cast<const float4*>(&sW[k2 * 64 + tx * 4]);
    FMA16(a, w)
  }
  __syncthreads();

  // stage A, K-half 1
  for (int i = tid; i < 64 * 64; i += 256) {
    int m = i >> 6, k2 = i & 63;
    int row = m0 + m;
    float v = 0.0f;
    if (row < M)
      v = dual ? S1[(size_t)row * 64 + k2] : S0[(size_t)row * 128 + 64 + k2];
    sA[k2 * 68 + m] = v;
  }
  __syncthreads();

#pragma unroll 8
  for (int k2 = 0; k2 < 64; ++k2) {
    const float4 a = *reinterpret_cast<const float4*>(&sA[k2 * 68 + ty * 4]);
    const float4 w = *reinterpret_cast<const float4*>(&sW[(64 + k2) * 64 + tx * 4]);
    FMA16(a, w)
  }

#pragma unroll
  for (int i = 0; i < 4; ++i) {
    int row = m0 + ty * 4 + i;
    if (row < M) {
      float4 o = make_float4(acc[i][0], acc[i][1], acc[i][2], acc[i][3]);
      if (doRelu) {
        o.x = fmaxf(o.x, 0.0f); o.y = fmaxf(o.y, 0.0f);
        o.z = fmaxf(o.z, 0.0f); o.w = fmaxf(o.w, 0.0f);
      }
      *reinterpret_cast<float4*>(&OUT[(size_t)row * outStride + colOff + tx * 4]) = o;
    }
  }
}

// --------------------------------------------- layer-2 epilogue (combine) ---
// H = relu(agg + bias + Z)   (agg already inv-scaled)
__global__ __launch_bounds__(256) void k_combine(
    const float* __restrict__ agg, const float* __restrict__ bias,
    const float* __restrict__ Z, float* __restrict__ H) {
  int idx = blockIdx.x * 256 + threadIdx.x;  // grid = NN*16 threads
  int n = idx >> 4;
  int q = (idx & 15) << 2;
  const float4 a = *reinterpret_cast<const float4*>(&agg[(size_t)n * 64 + q]);
  const float4 z = *reinterpret_cast<const float4*>(&Z[(size_t)n * 64 + q]);
  const float4 b = *reinterpret_cast<const float4*>(&bias[q]);
  float4 h;
  h.x = fmaxf(a.x + b.x + z.x, 0.0f);
  h.y = fmaxf(a.y + b.y + z.y, 0.0f);
  h.z = fmaxf(a.z + b.z + z.z, 0.0f);
  h.w = fmaxf(a.w + b.w + z.w, 0.0f);
  *reinterpret_cast<float4*>(&H[(size_t)n * 64 + q]) = h;
}

// ------------------------------------------------------------------ pool ----
__global__ __launch_bounds__(256) void k_pool(const float* __restrict__ H,
                                              const int* __restrict__ batch,
                                              float* __restrict__ gsum,
                                              float* __restrict__ gcnt) {
  int idx = blockIdx.x * 256 + threadIdx.x;  // NN*16 threads
  int n = idx >> 4;
  int q = (idx & 15) << 2;
  int b = batch[n];
  const float4 v = *reinterpret_cast<const float4*>(&H[(size_t)n * 64 + q]);
  float* p = &gsum[(size_t)b * 64 + q];
  unsafeAtomicAdd(p + 0, v.x);
  unsafeAtomicAdd(p + 1, v.y);
  unsafeAtomicAdd(p + 2, v.z);
  unsafeAtomicAdd(p + 3, v.w);
  if ((idx & 15) == 0) unsafeAtomicAdd(&gcnt[b], 1.0f);
}

// ------------------------------------------------------------------- MLP ----
__global__ __launch_bounds__(64) void k_mlp(
    const float* __restrict__ gsum, const float* __restrict__ gcnt,
    const float* __restrict__ w1, const float* __restrict__ b1,
    const float* __restrict__ w2, const float* __restrict__ b2,
    const float* __restrict__ w3, const float* __restrict__ b3,
    const float* __restrict__ w4, const float* __restrict__ b4,
    float* __restrict__ out) {
  __shared__ float sg[64], s1[64], s2[32], s3[32];
  int g = blockIdx.x, t = threadIdx.x;
  float cnt = fmaxf(gcnt[g], 1.0f);
  sg[t] = gsum[(size_t)g * 64 + t] / cnt;
  __syncthreads();
  float acc = b1[t];
  for (int k = 0; k < 64; ++k) acc += sg[k] * w1[k * 64 + t];
  s1[t] = fmaxf(acc, 0.0f);
  __syncthreads();
  if (t < 32) {
    acc = b2[t];
    for (int k = 0; k < 64; ++k) acc += s1[k] * w2[k * 32 + t];
    s2[t] = fmaxf(acc, 0.0f);
  }
  __syncthreads();
  if (t < 32) {
    acc = b3[t];
    for (int k = 0; k < 32; ++k) acc += s2[k] * w3[k * 32 + t];
    s3[t] = fmaxf(acc, 0.0f);
  }
  __syncthreads();
  if (t == 0) {
    acc = b4[0];
    for (int k = 0; k < 32; ++k) acc += s3[k] * w4[k];
    out[g] = acc;
  }
}

// ---------------------------------------------------------------- launch ----
extern "C" void kernel_launch(void* const* d_in, const int* in_sizes, int n_in,
                              void* d_out, int out_size, void* d_ws,
                              size_t ws_size, hipStream_t stream) {
  const float* x     = (const float*)d_in[0];
  const int*   ei    = (const int*)d_in[1];
  const int*   batch = (const int*)d_in[2];
  const int* src = ei;
  const int* dst = ei + NE;

  const float* c1_wl = (const float*)d_in[3];
  const float* c1_bl = (const float*)d_in[4];
  const float* c1_wr = (const float*)d_in[5];
  const float* c2_wl = (const float*)d_in[6];
  const float* c2_bl = (const float*)d_in[7];
  const float* c2_wr = (const float*)d_in[8];
  const float* c3_wl = (const float*)d_in[9];
  const float* c3_bl = (const float*)d_in[10];
  const float* c3_wr = (const float*)d_in[11];
  const float* c4_wl = (const float*)d_in[12];
  const float* c4_bl = (const float*)d_in[13];
  const float* c4_wr = (const float*)d_in[14];
  const float* l1w = (const float*)d_in[15];
  const float* l1b = (const float*)d_in[16];
  const float* l2w = (const float*)d_in[17];
  const float* l2b = (const float*)d_in[18];
  const float* l3w = (const float*)d_in[19];
  const float* l3b = (const float*)d_in[20];
  const float* l4w = (const float*)d_in[21];
  const float* l4b = (const float*)d_in[22];

  // ---- workspace carve-up
  float* ws = (float*)d_ws;
  float* inv  = ws;                         // NN
  float* agg  = inv + NN;                   // NN*64
  float* h1   = agg + (size_t)NN * 64;      // NN*128
  float* U    = h1 + (size_t)NN * 128;      // NN*64
  float* V    = U + (size_t)NN * 64;        // NN*64
  float* gsum = V + (size_t)NN * 64;        // NG*64
  float* gcnt = gsum + (size_t)NG * 64;     // NG
  int* cnt    = (int*)(gcnt + NG);          // NN
  int* off    = cnt + NN;                   // NN+1
  int* cursor = off + NN + 1;               // NN
  int* bsum   = cursor + NN;                // 512
  int* csr    = bsum + 512;                 // NE

  const int gE   = (NE + 255) / 256;  // 6250
  const int gN16 = NN * 16 / 256;     // 6250  (gather/combine/pool)
  const int gM   = (NN + 63) / 64;    // 1563  (gemm)
  const int gN   = NBLK_SCAN;         // 391

  hipMemsetAsync(cnt, 0, (size_t)NN * 4, stream);
  hipMemsetAsync(gsum, 0, (size_t)(NG * 64 + NG) * 4, stream);

  // ---- CSR build (once; reused by all 4 layers)
  k_count<<<gE, 256, 0, stream>>>(dst, cnt);
  k_scan1<<<gN, 256, 0, stream>>>(cnt, off, bsum);
  k_scan2<<<1, 512, 0, stream>>>(bsum);
  k_scan3<<<gN, 256, 0, stream>>>(off, bsum, cursor);
  k_invdeg<<<gN, 256, 0, stream>>>(cnt, inv);
  k_fill<<<gE, 256, 0, stream>>>(src, dst, cursor, csr);

  // ---- layer 1: h1 = relu([agg(x) | x] @ [[c1_wl],[c1_wr]] + c1_bl)
  k_gather<<<gN16, 256, 0, stream>>>(x, csr, off, inv, agg);
  k_gemm64<<<gM, 256, 0, stream>>>(agg, x, 1, c1_wl, c1_wr, 128, 0,  c1_bl, 1, h1, 128, NN);
  k_gemm64<<<gM, 256, 0, stream>>>(agg, x, 1, c1_wl, c1_wr, 128, 64, c1_bl, 1, h1, 128, NN);

  // ---- layer 2 (post-aggregate): U = h1@wl, V = h1@wr, h2 = relu(agg(U)+b+V)
  k_gemm64<<<gM, 256, 0, stream>>>(h1, nullptr, 0, c2_wl, nullptr, 64, 0, nullptr, 0, U, 64, NN);
  k_gemm64<<<gM, 256, 0, stream>>>(h1, nullptr, 0, c2_wr, nullptr, 64, 0, nullptr, 0, V, 64, NN);
  k_gather<<<gN16, 256, 0, stream>>>(U, csr, off, inv, agg);
  k_combine<<<gN16, 256, 0, stream>>>(agg, c2_bl, V, U);  // U = h2

  // ---- layer 3: V = relu([agg(h2) | h2] @ [[c3_wl],[c3_wr]] + c3_bl)
  k_gather<<<gN16, 256, 0, stream>>>(U, csr, off, inv, agg);
  k_gemm64<<<gM, 256, 0, stream>>>(agg, U, 1, c3_wl, c3_wr, 64, 0, c3_bl, 1, V, 64, NN);

  // ---- layer 4: U = relu([agg(h3) | h3] @ [[c4_wl],[c4_wr]] + c4_bl)
  k_gather<<<gN16, 256, 0, stream>>>(V, csr, off, inv, agg);
  k_gemm64<<<gM, 256, 0, stream>>>(agg, V, 1, c4_wl, c4_wr, 64, 0, c4_bl, 1, U, 64, NN);

  // ---- pool + MLP
  k_pool<<<gN16, 256, 0, stream>>>(U, batch, gsum, gcnt);
  k_mlp<<<NG, 64, 0, stream>>>(gsum, gcnt, l1w, l1b, l2w, l2b, l3w, l3b, l4w, l4b,
                               (float*)d_out);
}

// Round 3
// 837.176 us; speedup vs baseline: 7.0067x; 1.2822x over previous
//
#include <hip/hip_runtime.h>

#define NN 100000
#define NE 1600000
#define NG 1024
#define NBLK_SCAN ((NN + 255) / 256)  // 391

// ------------------------------------------------------------- CSR build ----
__global__ __launch_bounds__(256) void k_count(const int* __restrict__ dst,
                                               int* __restrict__ cnt) {
  int e = blockIdx.x * 256 + threadIdx.x;
  if (e < NE) atomicAdd(&cnt[dst[e]], 1);
}

__global__ __launch_bounds__(256) void k_scan1(const int* __restrict__ cnt,
                                               int* __restrict__ off,
                                               int* __restrict__ bsum) {
  __shared__ int s[256];
  int tid = threadIdx.x;
  int i = blockIdx.x * 256 + tid;
  int v = (i < NN) ? cnt[i] : 0;
  s[tid] = v;
  __syncthreads();
  for (int d = 1; d < 256; d <<= 1) {
    int t = (tid >= d) ? s[tid - d] : 0;
    __syncthreads();
    s[tid] += t;
    __syncthreads();
  }
  if (i < NN) off[i] = s[tid] - v;  // exclusive
  if (tid == 255) bsum[blockIdx.x] = s[255];
}

__global__ __launch_bounds__(512) void k_scan2(int* __restrict__ bsum) {
  __shared__ int s[512];
  int tid = threadIdx.x;
  int v = (tid < NBLK_SCAN) ? bsum[tid] : 0;
  s[tid] = v;
  __syncthreads();
  for (int d = 1; d < 512; d <<= 1) {
    int t = (tid >= d) ? s[tid - d] : 0;
    __syncthreads();
    s[tid] += t;
    __syncthreads();
  }
  if (tid < NBLK_SCAN) bsum[tid] = s[tid] - v;  // exclusive
}

__global__ __launch_bounds__(256) void k_scan3(int* __restrict__ off,
                                               const int* __restrict__ bsum,
                                               int* __restrict__ cursor) {
  int i = blockIdx.x * 256 + threadIdx.x;
  if (i < NN) {
    int o = off[i] + bsum[blockIdx.x];
    off[i] = o;
    cursor[i] = o;
  }
  if (i == 0) off[NN] = NE;
}

__global__ __launch_bounds__(256) void k_fill(const int* __restrict__ src,
                                              const int* __restrict__ dst,
                                              int* __restrict__ cursor,
                                              int* __restrict__ csr) {
  int e = blockIdx.x * 256 + threadIdx.x;
  if (e < NE) {
    int d = dst[e];
    int pos = atomicAdd(&cursor[d], 1);
    csr[pos] = src[e];
  }
}

__global__ __launch_bounds__(256) void k_invdeg(const int* __restrict__ cnt,
                                                float* __restrict__ inv) {
  int i = blockIdx.x * 256 + threadIdx.x;
  if (i < NN) inv[i] = 1.0f / fmaxf((float)cnt[i], 1.0f);
}

// graph segment boundaries in the SORTED batch array: gstart[g] = lower_bound(batch, g)
__global__ __launch_bounds__(256) void k_bounds(const int* __restrict__ batch,
                                                int* __restrict__ gstart) {
  int g = blockIdx.x * 256 + threadIdx.x;
  if (g > NG) return;
  int lo = 0, hi = NN;
  while (lo < hi) {
    int mid = (lo + hi) >> 1;
    if (batch[mid] < g) lo = mid + 1; else hi = mid;
  }
  gstart[g] = lo;
}

// --------------------------------------------------------- gather-aggregate -
// out[n] = inv[n]*sum_{e}(F[csr[e]])            (bias==null)
// out[n] = relu(inv[n]*sum + bias + Z[n])       (bias!=null, layer-2 epilogue)
// 16 thr/node, float4 lanes, 4-way edge unroll for MLP.
__global__ __launch_bounds__(256) void k_gather(const float* __restrict__ F,
                                                const int* __restrict__ csr,
                                                const int* __restrict__ off,
                                                const float* __restrict__ inv,
                                                const float* __restrict__ bias,
                                                const float* __restrict__ Z,
                                                float* __restrict__ out) {
  int idx = blockIdx.x * 256 + threadIdx.x;  // grid = NN*16 threads
  int n = idx >> 4;
  int q = (idx & 15) << 2;
  int beg = off[n], end = off[n + 1];
  float4 a0 = make_float4(0.f, 0.f, 0.f, 0.f);
  float4 a1 = a0, a2 = a0, a3 = a0;
  int e = beg;
  for (; e + 4 <= end; e += 4) {
    int s0 = csr[e], s1 = csr[e + 1], s2 = csr[e + 2], s3 = csr[e + 3];
    const float4 v0 = *reinterpret_cast<const float4*>(&F[(size_t)s0 * 64 + q]);
    const float4 v1 = *reinterpret_cast<const float4*>(&F[(size_t)s1 * 64 + q]);
    const float4 v2 = *reinterpret_cast<const float4*>(&F[(size_t)s2 * 64 + q]);
    const float4 v3 = *reinterpret_cast<const float4*>(&F[(size_t)s3 * 64 + q]);
    a0.x += v0.x; a0.y += v0.y; a0.z += v0.z; a0.w += v0.w;
    a1.x += v1.x; a1.y += v1.y; a1.z += v1.z; a1.w += v1.w;
    a2.x += v2.x; a2.y += v2.y; a2.z += v2.z; a2.w += v2.w;
    a3.x += v3.x; a3.y += v3.y; a3.z += v3.z; a3.w += v3.w;
  }
  for (; e < end; ++e) {
    int s0 = csr[e];
    const float4 v0 = *reinterpret_cast<const float4*>(&F[(size_t)s0 * 64 + q]);
    a0.x += v0.x; a0.y += v0.y; a0.z += v0.z; a0.w += v0.w;
  }
  float4 acc;
  acc.x = (a0.x + a1.x) + (a2.x + a3.x);
  acc.y = (a0.y + a1.y) + (a2.y + a3.y);
  acc.z = (a0.z + a1.z) + (a2.z + a3.z);
  acc.w = (a0.w + a1.w) + (a2.w + a3.w);
  float iv = inv[n];
  acc.x *= iv; acc.y *= iv; acc.z *= iv; acc.w *= iv;
  if (bias != nullptr) {
    const float4 b = *reinterpret_cast<const float4*>(&bias[q]);
    const float4 z = *reinterpret_cast<const float4*>(&Z[(size_t)n * 64 + q]);
    acc.x = fmaxf(acc.x + b.x + z.x, 0.0f);
    acc.y = fmaxf(acc.y + b.y + z.y, 0.0f);
    acc.z = fmaxf(acc.z + b.z + z.z, 0.0f);
    acc.w = fmaxf(acc.w + b.w + z.w, 0.0f);
  }
  *reinterpret_cast<float4*>(&out[(size_t)n * 64 + q]) = acc;
}

// ----------------------------------------------------------------- GEMM -----
// OUT[M x 64 cols] = act( A @ W + bias )
// dual==1: A = [S0 | S1] (each M x 64), W = [[WL],[WR]] stacked (wStride cols).
// dual==0: A = S0 (M x 128), W = WL (128 x wStride).
// grid.y: if colMulY, col block = 64*blockIdx.y of a wide W;
//         else blockIdx.y==1 switches to (WL2,WR2,OUT2) with colOff 0.
#define FMA16(A, W)                                                            \
  acc[0][0] += (A).x * (W).x; acc[0][1] += (A).x * (W).y;                      \
  acc[0][2] += (A).x * (W).z; acc[0][3] += (A).x * (W).w;                      \
  acc[1][0] += (A).y * (W).x; acc[1][1] += (A).y * (W).y;                      \
  acc[1][2] += (A).y * (W).z; acc[1][3] += (A).y * (W).w;                      \
  acc[2][0] += (A).z * (W).x; acc[2][1] += (A).z * (W).y;                      \
  acc[2][2] += (A).z * (W).z; acc[2][3] += (A).z * (W).w;                      \
  acc[3][0] += (A).w * (W).x; acc[3][1] += (A).w * (W).y;                      \
  acc[3][2] += (A).w * (W).z; acc[3][3] += (A).w * (W).w;

__global__ __launch_bounds__(256) void k_gemm64(
    const float* __restrict__ S0, const float* __restrict__ S1, int dual,
    const float* __restrict__ WL, const float* __restrict__ WR, int wStride,
    int colMulY,
    const float* __restrict__ WL2, const float* __restrict__ WR2,
    float* __restrict__ OUT2,
    const float* __restrict__ bias, int doRelu,
    float* __restrict__ OUT, int outStride, int M) {
  __shared__ float sA[64 * 68];
  __shared__ float sW[128 * 64];
  __shared__ float sB[64];
  const int tid = threadIdx.x;

  int colOff = 0;
  if (colMulY) {
    colOff = 64 * blockIdx.y;
  } else if (blockIdx.y == 1) {
    WL = WL2; WR = WR2; OUT = OUT2;
  }

  for (int i = tid; i < 128 * 64; i += 256) {
    int k = i >> 6, c = i & 63;
    float w;
    if (dual)
      w = (k < 64) ? WL[k * wStride + colOff + c]
                   : WR[(k - 64) * wStride + colOff + c];
    else
      w = WL[k * wStride + colOff + c];
    sW[i] = w;
  }
  if (tid < 64) sB[tid] = bias ? bias[colOff + tid] : 0.0f;

  const int m0 = blockIdx.x * 64;
  const int tx = tid & 15, ty = tid >> 4;

  // stage A, K-half 0
  for (int i = tid; i < 64 * 64; i += 256) {
    int m = i >> 6, k2 = i & 63;
    int row = m0 + m;
    float v = 0.0f;
    if (row < M)
      v = dual ? S0[(size_t)row * 64 + k2] : S0[(size_t)row * 128 + k2];
    sA[k2 * 68 + m] = v;
  }
  __syncthreads();

  float acc[4][4];
#pragma unroll
  for (int i = 0; i < 4; ++i)
#pragma unroll
    for (int j = 0; j < 4; ++j) acc[i][j] = sB[tx * 4 + j];

#pragma unroll 8
  for (int k2 = 0; k2 < 64; ++k2) {
    const float4 a = *reinterpret_cast<const float4*>(&sA[k2 * 68 + ty * 4]);
    const float4 w = *reinterpret_cast<const float4*>(&sW[k2 * 64 + tx * 4]);
    FMA16(a, w)
  }
  __syncthreads();

  // stage A, K-half 1
  for (int i = tid; i < 64 * 64; i += 256) {
    int m = i >> 6, k2 = i & 63;
    int row = m0 + m;
    float v = 0.0f;
    if (row < M)
      v = dual ? S1[(size_t)row * 64 + k2] : S0[(size_t)row * 128 + 64 + k2];
    sA[k2 * 68 + m] = v;
  }
  __syncthreads();

#pragma unroll 8
  for (int k2 = 0; k2 < 64; ++k2) {
    const float4 a = *reinterpret_cast<const float4*>(&sA[k2 * 68 + ty * 4]);
    const float4 w = *reinterpret_cast<const float4*>(&sW[(64 + k2) * 64 + tx * 4]);
    FMA16(a, w)
  }

#pragma unroll
  for (int i = 0; i < 4; ++i) {
    int row = m0 + ty * 4 + i;
    if (row < M) {
      float4 o = make_float4(acc[i][0], acc[i][1], acc[i][2], acc[i][3]);
      if (doRelu) {
        o.x = fmaxf(o.x, 0.0f); o.y = fmaxf(o.y, 0.0f);
        o.z = fmaxf(o.z, 0.0f); o.w = fmaxf(o.w, 0.0f);
      }
      *reinterpret_cast<float4*>(&OUT[(size_t)row * outStride + colOff + tx * 4]) = o;
    }
  }
}

// ----------------------------------------------- fused mean-pool + MLP ------
// one 64-thread block per graph; batch is sorted so each graph is a
// contiguous node range [gstart[g], gstart[g+1]) — no atomics.
__global__ __launch_bounds__(64) void k_poolmlp(
    const float* __restrict__ H, const int* __restrict__ gstart,
    const float* __restrict__ w1, const float* __restrict__ b1,
    const float* __restrict__ w2, const float* __restrict__ b2,
    const float* __restrict__ w3, const float* __restrict__ b3,
    const float* __restrict__ w4, const float* __restrict__ b4,
    float* __restrict__ out) {
  __shared__ float sg[64], s1[64], s2[32], s3[32];
  int g = blockIdx.x, t = threadIdx.x;
  int beg = gstart[g], end = gstart[g + 1];
  float acc = 0.0f;
#pragma unroll 4
  for (int n = beg; n < end; ++n) acc += H[(size_t)n * 64 + t];
  float cnt = fmaxf((float)(end - beg), 1.0f);
  sg[t] = acc / cnt;
  __syncthreads();
  acc = b1[t];
  for (int k = 0; k < 64; ++k) acc += sg[k] * w1[k * 64 + t];
  s1[t] = fmaxf(acc, 0.0f);
  __syncthreads();
  if (t < 32) {
    acc = b2[t];
    for (int k = 0; k < 64; ++k) acc += s1[k] * w2[k * 32 + t];
    s2[t] = fmaxf(acc, 0.0f);
  }
  __syncthreads();
  if (t < 32) {
    acc = b3[t];
    for (int k = 0; k < 32; ++k) acc += s2[k] * w3[k * 32 + t];
    s3[t] = fmaxf(acc, 0.0f);
  }
  __syncthreads();
  if (t == 0) {
    acc = b4[0];
    for (int k = 0; k < 32; ++k) acc += s3[k] * w4[k];
    out[g] = acc;
  }
}

// ---------------------------------------------------------------- launch ----
extern "C" void kernel_launch(void* const* d_in, const int* in_sizes, int n_in,
                              void* d_out, int out_size, void* d_ws,
                              size_t ws_size, hipStream_t stream) {
  const float* x     = (const float*)d_in[0];
  const int*   ei    = (const int*)d_in[1];
  const int*   batch = (const int*)d_in[2];
  const int* src = ei;
  const int* dst = ei + NE;

  const float* c1_wl = (const float*)d_in[3];
  const float* c1_bl = (const float*)d_in[4];
  const float* c1_wr = (const float*)d_in[5];
  const float* c2_wl = (const float*)d_in[6];
  const float* c2_bl = (const float*)d_in[7];
  const float* c2_wr = (const float*)d_in[8];
  const float* c3_wl = (const float*)d_in[9];
  const float* c3_bl = (const float*)d_in[10];
  const float* c3_wr = (const float*)d_in[11];
  const float* c4_wl = (const float*)d_in[12];
  const float* c4_bl = (const float*)d_in[13];
  const float* c4_wr = (const float*)d_in[14];
  const float* l1w = (const float*)d_in[15];
  const float* l1b = (const float*)d_in[16];
  const float* l2w = (const float*)d_in[17];
  const float* l2b = (const float*)d_in[18];
  const float* l3w = (const float*)d_in[19];
  const float* l3b = (const float*)d_in[20];
  const float* l4w = (const float*)d_in[21];
  const float* l4b = (const float*)d_in[22];

  // ---- workspace carve-up
  float* ws = (float*)d_ws;
  float* inv = ws;                        // NN
  float* B1  = inv + NN;                  // NN*64   (agg / h2 / h4)
  float* B2  = B1 + (size_t)NN * 64;      // NN*128  (h1)
  float* B3  = B2 + (size_t)NN * 128;     // NN*64   (U / agg scratch)
  float* B4  = B3 + (size_t)NN * 64;      // NN*64   (V / h3)
  int* cnt    = (int*)(B4 + (size_t)NN * 64);  // NN
  int* off    = cnt + NN;                 // NN+1
  int* cursor = off + NN + 1;             // NN
  int* bsum   = cursor + NN;              // 512
  int* gstart = bsum + 512;               // NG+1
  int* csr    = gstart + NG + 1 + 3;      // NE

  const int gE   = (NE + 255) / 256;  // 6250
  const int gN16 = NN * 16 / 256;     // 6250  (gather)
  const int gM   = (NN + 63) / 64;    // 1563  (gemm x)
  const int gN   = NBLK_SCAN;         // 391

  hipMemsetAsync(cnt, 0, (size_t)NN * 4, stream);

  // ---- CSR build (reused by all 4 layers) + graph bounds
  k_count<<<gE, 256, 0, stream>>>(dst, cnt);
  k_scan1<<<gN, 256, 0, stream>>>(cnt, off, bsum);
  k_scan2<<<1, 512, 0, stream>>>(bsum);
  k_scan3<<<gN, 256, 0, stream>>>(off, bsum, cursor);
  k_invdeg<<<gN, 256, 0, stream>>>(cnt, inv);
  k_fill<<<gE, 256, 0, stream>>>(src, dst, cursor, csr);
  k_bounds<<<5, 256, 0, stream>>>(batch, gstart);

  // ---- layer 1: B2(h1) = relu([agg(x) | x] @ [[c1_wl],[c1_wr]] + c1_bl)
  k_gather<<<gN16, 256, 0, stream>>>(x, csr, off, inv, nullptr, nullptr, B1);
  k_gemm64<<<dim3(gM, 2), 256, 0, stream>>>(B1, x, 1, c1_wl, c1_wr, 128, 1,
                                            nullptr, nullptr, nullptr,
                                            c1_bl, 1, B2, 128, NN);

  // ---- layer 2: B3 = h1@wl, B4 = h1@wr; B1(h2) = relu(agg(B3) + b + B4)
  k_gemm64<<<dim3(gM, 2), 256, 0, stream>>>(B2, nullptr, 0, c2_wl, nullptr, 64, 0,
                                            c2_wr, nullptr, B4,
                                            nullptr, 0, B3, 64, NN);
  k_gather<<<gN16, 256, 0, stream>>>(B3, csr, off, inv, c2_bl, B4, B1);

  // ---- layer 3: B4(h3) = relu([agg(h2) | h2] @ [[c3_wl],[c3_wr]] + c3_bl)
  k_gather<<<gN16, 256, 0, stream>>>(B1, csr, off, inv, nullptr, nullptr, B3);
  k_gemm64<<<dim3(gM, 1), 256, 0, stream>>>(B3, B1, 1, c3_wl, c3_wr, 64, 0,
                                            nullptr, nullptr, nullptr,
                                            c3_bl, 1, B4, 64, NN);

  // ---- layer 4: B1(h4) = relu([agg(h3) | h3] @ [[c4_wl],[c4_wr]] + c4_bl)
  k_gather<<<gN16, 256, 0, stream>>>(B4, csr, off, inv, nullptr, nullptr, B3);
  k_gemm64<<<dim3(gM, 1), 256, 0, stream>>>(B3, B4, 1, c4_wl, c4_wr, 64, 0,
                                            nullptr, nullptr, nullptr,
                                            c4_bl, 1, B1, 64, NN);

  // ---- fused pool + MLP (batch sorted -> contiguous segments, no atomics)
  k_poolmlp<<<NG, 64, 0, stream>>>(B1, gstart, l1w, l1b, l2w, l2b,
                                   l3w, l3b, l4w, l4b, (float*)d_out);
}